// Round 9
// baseline (389.386 us; speedup 1.0000x reference)
//
#include <hip/hip_runtime.h>

#define D 128
#define TN 64      // nodes per block
#define NR 3       // relations

typedef short short8 __attribute__((ext_vector_type(8)));
typedef float f32x4 __attribute__((ext_vector_type(4)));

// round-to-nearest-even f32 -> bf16 bits
__device__ __forceinline__ unsigned int f2bf(float x) {
    unsigned int u = __float_as_uint(x);
    return (u + 0x7fffu + ((u >> 16) & 1u)) >> 16;
}

// ---------------- h f32 -> bf16 (row-major [N][128]) + zero row at N ---------
__global__ __launch_bounds__(256) void conv_h_k(const float* __restrict__ h,
                                                unsigned short* __restrict__ hb,
                                                int n8, int n8tot) {
    int i = blockIdx.x * 256 + threadIdx.x;
    if (i >= n8tot) return;
    if (i >= n8) {  // zero row (gather sink)
        ((uint4*)hb)[i] = make_uint4(0u, 0u, 0u, 0u);
        return;
    }
    const float4* hp = (const float4*)h;
    float4 v0 = hp[2 * i + 0], v1 = hp[2 * i + 1];
    uint4 o;
    o.x = f2bf(v0.x) | (f2bf(v0.y) << 16);
    o.y = f2bf(v0.z) | (f2bf(v0.w) << 16);
    o.z = f2bf(v1.x) | (f2bf(v1.y) << 16);
    o.w = f2bf(v1.z) | (f2bf(v1.w) << 16);
    ((uint4*)hb)[i] = o;
}

// ---------------- W pack: B-fragment order [12][8][64][8] bf16 ---------------
// Wb kg index = r*4 + klocal/32; lane l supplies k = (l>>4)*8+j, col = cg*16+(l&15).
__global__ void pack_w_k(const float* __restrict__ W,
                         unsigned short* __restrict__ Wb) {
    int t = blockIdx.x * 256 + threadIdx.x;
    if (t >= 12 * 8 * 64) return;
    int lane = t & 63, cg = (t >> 6) & 7, kg = t >> 9;
    int col = cg * 16 + (lane & 15);
    int r = kg >> 2;
    int klocal = (kg & 3) * 32 + (lane >> 4) * 8;
    const float* Ws = W + ((size_t)r * D + klocal) * D + col;
    uint4 o;
    o.x = f2bf(Ws[0 * D]) | (f2bf(Ws[1 * D]) << 16);
    o.y = f2bf(Ws[2 * D]) | (f2bf(Ws[3 * D]) << 16);
    o.z = f2bf(Ws[4 * D]) | (f2bf(Ws[5 * D]) << 16);
    o.w = f2bf(Ws[6 * D]) | (f2bf(Ws[7 * D]) << 16);
    ((uint4*)Wb)[t] = o;
}

// ---------------- chain build: one pass, coalesced 8B writes -----------------
__global__ void chain_k(const int* __restrict__ src, const int* __restrict__ dst,
                        int* __restrict__ head, int2* __restrict__ chain,
                        int E, int N, int nbE) {
    int r = blockIdx.x / nbE;
    int i = (blockIdx.x - r * nbE) * 256 + threadIdx.x;
    if (i >= E) return;
    size_t gi = (size_t)r * E + i;
    int d = dst[gi];
    int s = src[gi];
    int old = atomicExch(&head[r * N + d], (int)gi);
    chain[gi] = make_int2(s, old);
}

// ---------------- fused: walk -> 2x(gather half -> MFMA half) -> epilogue ----
// Block = 512 threads, 64 output rows, K = 384 (3 rel x 128 feat).
// K split into two 64-feature halves: Ald [4 rowgrp][6 kg][64 lane] = 24 KB,
// idx[3][16][64] = 12 KB, degs/ovfs = 1.5 KB. Total ~37.6 KB -> 4 blocks/CU.
// Gather main path is BRANCHLESS: all 3 relations' 8 sink-padded loads issued
// before any accumulate (24 independent loads in flight per thread).
__global__ __launch_bounds__(512, 8) void fused_k(
    const unsigned short* __restrict__ hb, const int* __restrict__ head,
    const int2* __restrict__ chain, const unsigned short* __restrict__ Wb,
    float* __restrict__ out, int N) {
    __shared__ uint4 Ald[4 * 6 * 64];       // 24 KB
    __shared__ int idxs[NR][16][TN];        // 12 KB
    __shared__ int degs[NR][TN];
    __shared__ int ovfs[NR][TN];

    const int tid = threadIdx.x;
    const int blk = blockIdx.x;

    // ---- phase W: walk chains into LDS (192 walkers) ----
    if (tid < NR * TN) {
        int r = tid / TN, nl = tid - r * TN;
        int n = blk * TN + nl;
        if (n >= N) n = N - 1;
        int e = head[r * N + n];
        int d = 0, ov = -1;
        while (e >= 0) {
            if (d == 16) ov = e;            // 17th edge onward: overflow walk
            int2 ce = chain[e];
            if (d < 16) idxs[r][d][nl] = ce.x;
            ++d;
            e = ce.y;
        }
        degs[r][nl] = d;
        ovfs[r][nl] = ov;
    }
    __syncthreads();

    const int lane = tid & 63;
    const int kgl = (tid >> 6) & 1;             // k sub-block within half
    const int rg = tid >> 7;                    // rowgrp 0..3
    const int nl = rg * 16 + (lane & 15);       // local node 0..63
    const int w = tid >> 6;                     // wave 0..7
    const int wr = w >> 2, wc = w & 3;          // 2 x 4 wave grid for MFMA

    const short8* Ap = (const short8*)Ald;
    const short8* Bp = (const short8*)Wb;
    f32x4 acc[2][2];
#pragma unroll
    for (int m = 0; m < 2; ++m)
#pragma unroll
        for (int n = 0; n < 2; ++n) acc[m][n] = (f32x4){0.f, 0.f, 0.f, 0.f};

    int cnt[NR];
#pragma unroll
    for (int r = 0; r < NR; ++r) cnt[r] = degs[r][nl];

#define ACC8(u)                                                              \
    {                                                                        \
        a0 += __uint_as_float((u).x << 16);                                  \
        a1 += __uint_as_float((u).x & 0xffff0000u);                          \
        a2 += __uint_as_float((u).y << 16);                                  \
        a3 += __uint_as_float((u).y & 0xffff0000u);                          \
        a4 += __uint_as_float((u).z << 16);                                  \
        a5 += __uint_as_float((u).z & 0xffff0000u);                          \
        a6 += __uint_as_float((u).w << 16);                                  \
        a7 += __uint_as_float((u).w & 0xffff0000u);                          \
    }
#define GLD(s) (*(const uint4*)(hb + ((size_t)(s) << 7) + c))

#pragma unroll
    for (int khalf = 0; khalf < 2; ++khalf) {
        const int c = khalf * 64 + kgl * 32 + ((lane >> 4) << 3);

        // ---- issue ALL relations' first-8 loads (branchless, sink-padded) ----
        uint4 u[NR][8];
#pragma unroll
        for (int r = 0; r < NR; ++r)
#pragma unroll
            for (int j = 0; j < 8; ++j) {
                int s = (j < cnt[r]) ? idxs[r][j][nl] : N;
                u[r][j] = GLD(s);
            }

        // ---- accumulate per relation; rare tails after main loads in flight --
#pragma unroll
        for (int r = 0; r < NR; ++r) {
            float a0 = 0, a1 = 0, a2 = 0, a3 = 0, a4 = 0, a5 = 0, a6 = 0,
                  a7 = 0;
#pragma unroll
            for (int j = 0; j < 8; ++j) ACC8(u[r][j]);
            if (cnt[r] > 8) {   // ~7% of threads
                uint4 v[8];
#pragma unroll
                for (int j = 0; j < 8; ++j) {
                    int s = (j + 8 < cnt[r]) ? idxs[r][j + 8][nl] : N;
                    v[j] = GLD(s);
                }
#pragma unroll
                for (int j = 0; j < 8; ++j) ACC8(v[j]);
                if (cnt[r] > 16) {  // super rare: finish via chain walk
                    int e = ovfs[r][nl];
                    while (e >= 0) {
                        int2 ce = chain[e];
                        uint4 uu = GLD(ce.x);
                        ACC8(uu);
                        e = ce.y;
                    }
                }
            }
            float sc = 1.0f / (3.0f * fmaxf((float)cnt[r], 1.0f));
            uint4 o;
            o.x = f2bf(a0 * sc) | (f2bf(a1 * sc) << 16);
            o.y = f2bf(a2 * sc) | (f2bf(a3 * sc) << 16);
            o.z = f2bf(a4 * sc) | (f2bf(a5 * sc) << 16);
            o.w = f2bf(a6 * sc) | (f2bf(a7 * sc) << 16);
            Ald[((rg * 6 + r * 2 + kgl) << 6) + lane] = o;
        }
        __syncthreads();

        // ---- MFMA this half: 6 kg (3 rel x 2 k-blocks) ----
#pragma unroll
        for (int r = 0; r < NR; ++r)
#pragma unroll
            for (int kb = 0; kb < 2; ++kb) {
                int kgA = r * 2 + kb;                   // Ald kg index
                int kgB = r * 4 + khalf * 2 + kb;       // Wb kg index
                short8 a[2], b[2];
#pragma unroll
                for (int m = 0; m < 2; ++m)
                    a[m] = Ap[(((wr * 2 + m) * 6 + kgA) << 6) + lane];
#pragma unroll
                for (int n = 0; n < 2; ++n)
                    b[n] = Bp[(((size_t)kgB * 8) + wc * 2 + n) * 64 + lane];
#pragma unroll
                for (int m = 0; m < 2; ++m)
#pragma unroll
                    for (int n = 0; n < 2; ++n)
                        acc[m][n] = __builtin_amdgcn_mfma_f32_16x16x32_bf16(
                            a[m], b[n], acc[m][n], 0, 0, 0);
            }
        __syncthreads();
    }
#undef ACC8
#undef GLD

    // epilogue: out = bf2f(hb) + acc. D layout: col=lane&15, row=(lane>>4)*4+reg
    int col0 = wc * 32 + (lane & 15);
    int rloc = wr * 32 + ((lane >> 4) << 2);
#pragma unroll
    for (int m = 0; m < 2; ++m)
#pragma unroll
        for (int rr = 0; rr < 4; ++rr) {
            int row = blk * TN + rloc + m * 16 + rr;
            if (row < N) {
                const unsigned short* ap = hb + ((size_t)row << 7) + col0;
                float* op = out + ((size_t)row << 7) + col0;
#pragma unroll
                for (int n = 0; n < 2; ++n)
                    op[n * 16] =
                        __uint_as_float((unsigned int)ap[n * 16] << 16) +
                        acc[m][n][rr];
            }
        }
}

extern "C" void kernel_launch(void* const* d_in, const int* in_sizes, int n_in,
                              void* d_out, int out_size, void* d_ws, size_t ws_size,
                              hipStream_t stream) {
    const float* h = (const float*)d_in[0];
    const float* W = (const float*)d_in[1];
    const int* src = (const int*)d_in[2];
    const int* dst = (const int*)d_in[3];
    float* out = (float*)d_out;

    const int N = in_sizes[0] / D;     // 100000
    const int E = in_sizes[2] / NR;    // 500000
    const int RN = NR * N;
    const int nbE = (E + 255) / 256;

    auto al16 = [](size_t x) { return (x + 15) & ~(size_t)15; };
    size_t sz_hb = al16((size_t)(N + 1) * D * 2);   // +1 zero row
    size_t sz_Wb = al16((size_t)12 * 8 * 64 * 8 * 2);
    size_t sz_head = al16((size_t)RN * 4);

    char* p = (char*)d_ws;
    unsigned short* hb = (unsigned short*)p; p += sz_hb;
    unsigned short* Wb = (unsigned short*)p; p += sz_Wb;
    int*  head  = (int*)p;  p += sz_head;
    int2* chain = (int2*)p;

    hipMemsetAsync(head, 0xFF, (size_t)RN * 4, stream);   // head = -1
    int n8 = N * D / 8, n8tot = (N + 1) * D / 8;
    conv_h_k<<<(n8tot + 255) / 256, 256, 0, stream>>>(h, hb, n8, n8tot);
    pack_w_k<<<(12 * 8 * 64 + 255) / 256, 256, 0, stream>>>(W, Wb);
    chain_k<<<NR * nbE, 256, 0, stream>>>(src, dst, head, chain, E, N, nbE);

    int nb = (N + TN - 1) / TN;
    fused_k<<<nb, 512, 0, stream>>>(hb, head, chain, Wb, out, N);
}

// Round 10
// 228.113 us; speedup vs baseline: 1.7070x; 1.7070x over previous
//
#include <hip/hip_runtime.h>

#define D 128
#define TN 64      // nodes per block
#define NR 3       // relations
#define PAD 16     // csr slots per (rel,node)

typedef short short8 __attribute__((ext_vector_type(8)));
typedef float f32x4 __attribute__((ext_vector_type(4)));

// round-to-nearest-even f32 -> bf16 bits
__device__ __forceinline__ unsigned int f2bf(float x) {
    unsigned int u = __float_as_uint(x);
    return (u + 0x7fffu + ((u >> 16) & 1u)) >> 16;
}

// ---------------- prep: h f32->bf16 (+zero sink row) AND W pack --------------
// Blocks [0, nbConv): convert h. Blocks [nbConv, nbConv+24): pack W into
// B-fragment order [12][8][64][8] bf16 (kg = r*4 + klocal/32).
__global__ __launch_bounds__(256) void prep_k(const float* __restrict__ h,
                                              unsigned short* __restrict__ hb,
                                              const float* __restrict__ W,
                                              unsigned short* __restrict__ Wb,
                                              int n8, int n8tot, int nbConv) {
    if ((int)blockIdx.x < nbConv) {
        int i = blockIdx.x * 256 + threadIdx.x;
        if (i >= n8tot) return;
        if (i >= n8) {  // zero row (gather sink)
            ((uint4*)hb)[i] = make_uint4(0u, 0u, 0u, 0u);
            return;
        }
        const float4* hp = (const float4*)h;
        float4 v0 = hp[2 * i + 0], v1 = hp[2 * i + 1];
        uint4 o;
        o.x = f2bf(v0.x) | (f2bf(v0.y) << 16);
        o.y = f2bf(v0.z) | (f2bf(v0.w) << 16);
        o.z = f2bf(v1.x) | (f2bf(v1.y) << 16);
        o.w = f2bf(v1.z) | (f2bf(v1.w) << 16);
        ((uint4*)hb)[i] = o;
    } else {
        int t = ((int)blockIdx.x - nbConv) * 256 + threadIdx.x;
        if (t >= 12 * 8 * 64) return;
        int lane = t & 63, cg = (t >> 6) & 7, kg = t >> 9;
        int col = cg * 16 + (lane & 15);
        int r = kg >> 2;
        int klocal = (kg & 3) * 32 + (lane >> 4) * 8;
        const float* Ws = W + ((size_t)r * D + klocal) * D + col;
        uint4 o;
        o.x = f2bf(Ws[0 * D]) | (f2bf(Ws[1 * D]) << 16);
        o.y = f2bf(Ws[2 * D]) | (f2bf(Ws[3 * D]) << 16);
        o.z = f2bf(Ws[4 * D]) | (f2bf(Ws[5 * D]) << 16);
        o.w = f2bf(Ws[6 * D]) | (f2bf(Ws[7 * D]) << 16);
        ((uint4*)Wb)[t] = o;
    }
}

// ---------------- chain build: one pass, coalesced 8B writes -----------------
__global__ void chain_k(const int* __restrict__ src, const int* __restrict__ dst,
                        int* __restrict__ head, int2* __restrict__ chain,
                        int E, int N, int nbE) {
    int r = blockIdx.x / nbE;
    int i = (blockIdx.x - r * nbE) * 256 + threadIdx.x;
    if (i >= E) return;
    size_t gi = (size_t)r * E + i;
    int d = dst[gi];
    int s = src[gi];
    int old = atomicExch(&head[r * N + d], (int)gi);
    chain[gi] = make_int2(s, old);
}

// ---------------- flatten: chain -> padded CSR (one thread per (r,node)) -----
// csr[rn*PAD+j] = first PAD src ids; deg[rn] = full degree;
// ovfp[rn] = chain ptr of edge #17 (or -1) for the rare deg>PAD tail.
__global__ void flat_k(const int* __restrict__ head,
                       const int2* __restrict__ chain, int* __restrict__ csr,
                       int* __restrict__ deg, int* __restrict__ ovfp, int RN) {
    int rn = blockIdx.x * 256 + threadIdx.x;
    if (rn >= RN) return;
    int e = head[rn];
    int d = 0, ov = -1;
    int* cp = csr + ((size_t)rn << 4);
    while (e >= 0) {
        if (d == PAD) ov = e;
        int2 ce = chain[e];
        if (d < PAD) cp[d] = ce.x;
        ++d;
        e = ce.y;
    }
    deg[rn] = d;
    ovfp[rn] = ov;
}

// ---------------- fused: stage CSR -> 2x(gather half -> MFMA half) -> epilogue
// Block = 512 threads, 64 output rows, K = 384 (3 rel x 128 feat).
// LDS: Ald 24 KB + ilist 12 KB + degs 0.75 KB = ~37.6 KB -> 4 blocks/CU.
__global__ __launch_bounds__(512, 8) void fused_k(
    const unsigned short* __restrict__ hb, const int* __restrict__ csr,
    const int* __restrict__ deg, const int* __restrict__ ovfp,
    const int2* __restrict__ chain, const unsigned short* __restrict__ Wb,
    float* __restrict__ out, int N) {
    __shared__ uint4 Ald[4 * 6 * 64];       // 24 KB
    __shared__ int ilist[NR][PAD][TN];      // 12 KB
    __shared__ int degs_s[NR][TN];

    const int tid = threadIdx.x;
    const int blk = blockIdx.x;

    // ---- phase S: stage csr + deg into LDS (coalesced int4 reads) ----
    {
        int i = tid;                        // 768 int4 total, 512 threads
        for (; i < NR * TN * (PAD / 4); i += 512) {
            int jv = i & 3;
            int nl = (i >> 2) & (TN - 1);
            int r = i >> 8;
            int n = blk * TN + nl;
            if (n >= N) n = N - 1;
            int4 v = ((const int4*)(csr + ((size_t)(r * N + n) << 4)))[jv];
            ilist[r][jv * 4 + 0][nl] = v.x;
            ilist[r][jv * 4 + 1][nl] = v.y;
            ilist[r][jv * 4 + 2][nl] = v.z;
            ilist[r][jv * 4 + 3][nl] = v.w;
        }
        if (tid < NR * TN) {
            int r = tid / TN, nl = tid - r * TN;
            int n = blk * TN + nl;
            if (n >= N) n = N - 1;
            degs_s[r][nl] = deg[r * N + n];
        }
    }
    __syncthreads();

    const int lane = tid & 63;
    const int kgl = (tid >> 6) & 1;             // k sub-block within half
    const int rg = tid >> 7;                    // rowgrp 0..3
    const int nl = rg * 16 + (lane & 15);       // local node 0..63
    const int w = tid >> 6;                     // wave 0..7
    const int wr = w >> 2, wc = w & 3;          // 2 x 4 wave grid for MFMA
    int n_node = blk * TN + nl;
    if (n_node >= N) n_node = N - 1;

    const short8* Ap = (const short8*)Ald;
    const short8* Bp = (const short8*)Wb;
    f32x4 acc[2][2];
#pragma unroll
    for (int m = 0; m < 2; ++m)
#pragma unroll
        for (int n = 0; n < 2; ++n) acc[m][n] = (f32x4){0.f, 0.f, 0.f, 0.f};

    int cnt[NR];
#pragma unroll
    for (int r = 0; r < NR; ++r) cnt[r] = degs_s[r][nl];

#define ACC8(u)                                                              \
    {                                                                        \
        a0 += __uint_as_float((u).x << 16);                                  \
        a1 += __uint_as_float((u).x & 0xffff0000u);                          \
        a2 += __uint_as_float((u).y << 16);                                  \
        a3 += __uint_as_float((u).y & 0xffff0000u);                          \
        a4 += __uint_as_float((u).z << 16);                                  \
        a5 += __uint_as_float((u).z & 0xffff0000u);                          \
        a6 += __uint_as_float((u).w << 16);                                  \
        a7 += __uint_as_float((u).w & 0xffff0000u);                          \
    }
#define GLD(s) (*(const uint4*)(hb + ((size_t)(s) << 7) + c))

#pragma unroll
    for (int khalf = 0; khalf < 2; ++khalf) {
        const int c = khalf * 64 + kgl * 32 + ((lane >> 4) << 3);
        for (int r = 0; r < NR; ++r) {
            int cr = cnt[r];
            float a0 = 0, a1 = 0, a2 = 0, a3 = 0, a4 = 0, a5 = 0, a6 = 0,
                  a7 = 0;
            {   // first 8, branchless sink-padded (8 loads in flight)
                int s0 = (0 < cr) ? ilist[r][0][nl] : N;
                int s1 = (1 < cr) ? ilist[r][1][nl] : N;
                int s2 = (2 < cr) ? ilist[r][2][nl] : N;
                int s3 = (3 < cr) ? ilist[r][3][nl] : N;
                int s4 = (4 < cr) ? ilist[r][4][nl] : N;
                int s5 = (5 < cr) ? ilist[r][5][nl] : N;
                int s6 = (6 < cr) ? ilist[r][6][nl] : N;
                int s7 = (7 < cr) ? ilist[r][7][nl] : N;
                uint4 u0 = GLD(s0), u1 = GLD(s1), u2 = GLD(s2), u3 = GLD(s3);
                uint4 u4 = GLD(s4), u5 = GLD(s5), u6 = GLD(s6), u7 = GLD(s7);
                ACC8(u0); ACC8(u1); ACC8(u2); ACC8(u3);
                ACC8(u4); ACC8(u5); ACC8(u6); ACC8(u7);
            }
            if (cr > 8) {   // ~7% of threads
                int s0 = (8 < cr) ? ilist[r][8][nl] : N;
                int s1 = (9 < cr) ? ilist[r][9][nl] : N;
                int s2 = (10 < cr) ? ilist[r][10][nl] : N;
                int s3 = (11 < cr) ? ilist[r][11][nl] : N;
                int s4 = (12 < cr) ? ilist[r][12][nl] : N;
                int s5 = (13 < cr) ? ilist[r][13][nl] : N;
                int s6 = (14 < cr) ? ilist[r][14][nl] : N;
                int s7 = (15 < cr) ? ilist[r][15][nl] : N;
                uint4 u0 = GLD(s0), u1 = GLD(s1), u2 = GLD(s2), u3 = GLD(s3);
                uint4 u4 = GLD(s4), u5 = GLD(s5), u6 = GLD(s6), u7 = GLD(s7);
                ACC8(u0); ACC8(u1); ACC8(u2); ACC8(u3);
                ACC8(u4); ACC8(u5); ACC8(u6); ACC8(u7);
                if (cr > PAD) {  // super rare: finish via chain walk
                    int e = ovfp[r * N + n_node];
                    while (e >= 0) {
                        int2 ce = chain[e];
                        uint4 uu = GLD(ce.x);
                        ACC8(uu);
                        e = ce.y;
                    }
                }
            }
            float sc = 1.0f / (3.0f * fmaxf((float)cr, 1.0f));
            uint4 o;
            o.x = f2bf(a0 * sc) | (f2bf(a1 * sc) << 16);
            o.y = f2bf(a2 * sc) | (f2bf(a3 * sc) << 16);
            o.z = f2bf(a4 * sc) | (f2bf(a5 * sc) << 16);
            o.w = f2bf(a6 * sc) | (f2bf(a7 * sc) << 16);
            Ald[((rg * 6 + r * 2 + kgl) << 6) + lane] = o;
        }
        __syncthreads();

        // ---- MFMA this half: 6 kg (3 rel x 2 k-blocks) ----
#pragma unroll
        for (int r = 0; r < NR; ++r)
#pragma unroll
            for (int kb = 0; kb < 2; ++kb) {
                int kgA = r * 2 + kb;                   // Ald kg index
                int kgB = r * 4 + khalf * 2 + kb;       // Wb kg index
                short8 a[2], b[2];
#pragma unroll
                for (int m = 0; m < 2; ++m)
                    a[m] = Ap[(((wr * 2 + m) * 6 + kgA) << 6) + lane];
#pragma unroll
                for (int n = 0; n < 2; ++n)
                    b[n] = Bp[(((size_t)kgB * 8) + wc * 2 + n) * 64 + lane];
#pragma unroll
                for (int m = 0; m < 2; ++m)
#pragma unroll
                    for (int n = 0; n < 2; ++n)
                        acc[m][n] = __builtin_amdgcn_mfma_f32_16x16x32_bf16(
                            a[m], b[n], acc[m][n], 0, 0, 0);
            }
        __syncthreads();
    }
#undef ACC8
#undef GLD

    // epilogue: out = bf2f(hb) + acc. D layout: col=lane&15, row=(lane>>4)*4+reg
    int col0 = wc * 32 + (lane & 15);
    int rloc = wr * 32 + ((lane >> 4) << 2);
#pragma unroll
    for (int m = 0; m < 2; ++m)
#pragma unroll
        for (int rr = 0; rr < 4; ++rr) {
            int row = blk * TN + rloc + m * 16 + rr;
            if (row < N) {
                const unsigned short* ap = hb + ((size_t)row << 7) + col0;
                float* op = out + ((size_t)row << 7) + col0;
#pragma unroll
                for (int n = 0; n < 2; ++n)
                    op[n * 16] =
                        __uint_as_float((unsigned int)ap[n * 16] << 16) +
                        acc[m][n][rr];
            }
        }
}

extern "C" void kernel_launch(void* const* d_in, const int* in_sizes, int n_in,
                              void* d_out, int out_size, void* d_ws, size_t ws_size,
                              hipStream_t stream) {
    const float* h = (const float*)d_in[0];
    const float* W = (const float*)d_in[1];
    const int* src = (const int*)d_in[2];
    const int* dst = (const int*)d_in[3];
    float* out = (float*)d_out;

    const int N = in_sizes[0] / D;     // 100000
    const int E = in_sizes[2] / NR;    // 500000
    const int RN = NR * N;
    const int nbE = (E + 255) / 256;

    auto al16 = [](size_t x) { return (x + 15) & ~(size_t)15; };
    size_t sz_hb = al16((size_t)(N + 1) * D * 2);   // +1 zero row
    size_t sz_Wb = al16((size_t)12 * 8 * 64 * 8 * 2);
    size_t sz_head = al16((size_t)RN * 4);
    size_t sz_chain = al16((size_t)NR * E * 8);
    size_t sz_csr = al16((size_t)RN * PAD * 4);
    size_t sz_deg = al16((size_t)RN * 4);

    char* p = (char*)d_ws;
    unsigned short* hb = (unsigned short*)p; p += sz_hb;
    unsigned short* Wb = (unsigned short*)p; p += sz_Wb;
    int*  head  = (int*)p;  p += sz_head;
    int2* chain = (int2*)p; p += sz_chain;
    int*  csr   = (int*)p;  p += sz_csr;
    int*  deg   = (int*)p;  p += sz_deg;
    int*  ovfp  = (int*)p;

    hipMemsetAsync(head, 0xFF, (size_t)RN * 4, stream);   // head = -1
    int n8 = N * D / 8, n8tot = (N + 1) * D / 8;
    int nbConv = (n8tot + 255) / 256;
    prep_k<<<nbConv + 24, 256, 0, stream>>>(h, hb, W, Wb, n8, n8tot, nbConv);
    chain_k<<<NR * nbE, 256, 0, stream>>>(src, dst, head, chain, E, N, nbE);
    flat_k<<<(RN + 255) / 256, 256, 0, stream>>>(head, chain, csr, deg, ovfp, RN);

    int nb = (N + TN - 1) / TN;
    fused_k<<<nb, 512, 0, stream>>>(hb, csr, deg, ovfp, chain, Wb, out, N);
}